// Round 3
// baseline (186.252 us; speedup 1.0000x reference)
//
#include <hip/hip_runtime.h>

typedef float f2 __attribute__((ext_vector_type(2)));

namespace {
constexpr int kB = 4;
constexpr int kN = 4096;             // points per set per batch (N == M)
constexpr int kPts = kB * kN;        // per set = 16384
constexpr int kP = 2 * kPts;         // all per-point mins = 32768
constexpr int kBlk = 256;
constexpr int kSplit = 16;           // blocks splitting the inner scan
constexpr int kChunk = kN / kSplit;  // 256 other-points per block
constexpr int kChunkRecs = kChunk / 4;                // 64 records
constexpr int kGrid = (kN / kBlk) * kSplit * kB * 2;  // 2048 blocks
constexpr float kInf = 3.4e38f;
}

// 4 packed points: a={x0,x1,y0,y1} b={z0,z1,w0,w1} c,d = points 2,3.
// w = ||p||^2. 64-B aligned so the wave-uniform load merges to s_load_dwordx16.
struct alignas(64) Rec4 {
  float4 a, b, c, d;
};

// Monotone float<->uint map: unsigned atomicMin orders all floats (partial
// e = ||y||^2 - 2 x.y can be negative).
__device__ __forceinline__ unsigned enc(float f) {
  unsigned u = __float_as_uint(f);
  return (u & 0x80000000u) ? ~u : (u | 0x80000000u);
}
__device__ __forceinline__ float dec(unsigned k) {
  return __uint_as_float((k & 0x80000000u) ? (k ^ 0x80000000u) : ~k);
}

// ws layout: [keys: kP u32][pack: 2*kB*kN/4 Rec4, 64B-aligned][counter: u32]

// Pack points as Rec4s (set 0 = target, set 1 = source), init keys + counter.
__global__ __launch_bounds__(kBlk) void cham_prep_kernel(
    const float* __restrict__ src, const float* __restrict__ tgt,
    float* __restrict__ packf, unsigned* __restrict__ keys,
    unsigned* __restrict__ counter) {
  int i = blockIdx.x * kBlk + threadIdx.x;  // grid covers exactly kP points
  const float* p =
      (i < kPts) ? (tgt + (size_t)i * 3) : (src + (size_t)(i - kPts) * 3);
  float x = p[0], y = p[1], z = p[2];
  float w = fmaf(x, x, fmaf(y, y, z * z));
  int rec = i >> 2, sub = i & 3;
  int pair = sub >> 1, k = sub & 1;
  float* rp = packf + (size_t)rec * 16 + pair * 8 + k;
  rp[0] = x;
  rp[2] = y;
  rp[4] = z;
  rp[6] = w;
  keys[i] = 0xFFFFFFFFu;  // encodes +max for atomicMin
  if (i == 0) *counter = 0u;
}

// One thread = one own point; scans a 256-point chunk of the other set.
// min||x-y||^2 = ||x||^2 + min(||y||^2 - 2 x.y). Inner: 1 s_load_dwordx16 +
// 8 v_pk_* + 2 v_min3 per 4 points. Last finishing block sums all keys.
__global__ __launch_bounds__(kBlk) void cham_min_kernel(
    const float* __restrict__ src, const float* __restrict__ tgt,
    const Rec4* __restrict__ pack, unsigned* __restrict__ keys,
    unsigned* __restrict__ counter, float* __restrict__ out) {
  const int dir = blockIdx.z;  // 0: s->t (other=tgt=set0), 1: t->s
  const int b = blockIdx.y;
  const int chunk = blockIdx.x & (kSplit - 1);
  const int ntile = blockIdx.x >> 4;  // kSplit == 16
  const int n = ntile * kBlk + threadIdx.x;

  const float* own = dir ? tgt : src;
  const float* p = own + ((size_t)b * kN + n) * 3;
  const float x = p[0], y = p[1], z = p[2];
  const float w = fmaf(x, x, fmaf(y, y, z * z));
  const f2 NX = {-2.0f * x, -2.0f * x};
  const f2 NY = {-2.0f * y, -2.0f * y};
  const f2 NZ = {-2.0f * z, -2.0f * z};

  const Rec4* __restrict__ q =
      pack + ((size_t)dir * kB + b) * (kN / 4) + chunk * kChunkRecs;

  float best0 = kInf, best1 = kInf;
#pragma unroll 4
  for (int r = 0; r < kChunkRecs; ++r) {
    Rec4 rc = q[r];
    f2 X0 = {rc.a.x, rc.a.y}, Y0 = {rc.a.z, rc.a.w};
    f2 Z0 = {rc.b.x, rc.b.y}, W0 = {rc.b.z, rc.b.w};
    f2 e0 = __builtin_elementwise_fma(
                NX, X0, __builtin_elementwise_fma(NY, Y0, NZ * Z0)) +
            W0;
    f2 X1 = {rc.c.x, rc.c.y}, Y1 = {rc.c.z, rc.c.w};
    f2 Z1 = {rc.d.x, rc.d.y}, W1 = {rc.d.z, rc.d.w};
    f2 e1 = __builtin_elementwise_fma(
                NX, X1, __builtin_elementwise_fma(NY, Y1, NZ * Z1)) +
            W1;
    best0 = fminf(best0, fminf(e0.x, e0.y));  // v_min3
    best1 = fminf(best1, fminf(e1.x, e1.y));
  }
  const float best = fminf(best0, best1) + w;
  atomicMin(&keys[((size_t)dir * kB + b) * kN + n], enc(best));

  // Fused final reduction: last block to arrive sums everything.
  __threadfence();  // release our atomicMin results (agent scope)
  __shared__ int lastFlag;
  if (threadIdx.x == 0)
    lastFlag = (atomicAdd(counter, 1u) == (unsigned)(kGrid - 1));
  __syncthreads();
  if (!lastFlag) return;
  __threadfence();  // acquire: invalidate caches so key reads are coherent

  const uint4* __restrict__ k4 = (const uint4*)keys;
  float acc = 0.0f;
#pragma unroll 4
  for (int i = threadIdx.x; i < kP / 4; i += kBlk) {
    uint4 v = k4[i];
    acc += (dec(v.x) + dec(v.y)) + (dec(v.z) + dec(v.w));
  }
  __shared__ float red[kBlk];
  red[threadIdx.x] = acc;
  __syncthreads();
  for (int s = kBlk / 2; s > 0; s >>= 1) {
    if (threadIdx.x < s) red[threadIdx.x] += red[threadIdx.x + s];
    __syncthreads();
  }
  // mean_b[mean_n s2t + mean_m t2s] = total / (B*N) since N == M
  if (threadIdx.x == 0) out[0] = red[0] * (1.0f / kPts);
}

extern "C" void kernel_launch(void* const* d_in, const int* in_sizes, int n_in,
                              void* d_out, int out_size, void* d_ws,
                              size_t ws_size, hipStream_t stream) {
  const float* src = (const float*)d_in[0];  // (B, N, 3) fp32
  const float* tgt = (const float*)d_in[1];  // (B, M, 3) fp32
  float* out = (float*)d_out;                // scalar fp32

  unsigned* keys = (unsigned*)d_ws;                       // 128 KB
  float* packf = (float*)((char*)d_ws + (size_t)kP * 4);  // 512 KB, 64B-aligned
  unsigned* counter = (unsigned*)((char*)d_ws + (size_t)kP * 4 + (size_t)kP * 16);

  cham_prep_kernel<<<dim3(kP / kBlk), kBlk, 0, stream>>>(src, tgt, packf, keys,
                                                         counter);

  // (16 tiles * 16 splits, B, 2 dirs) = 2048 blocks -> 8/CU, full occupancy
  dim3 grid(kN / kBlk * kSplit, kB, 2);
  cham_min_kernel<<<grid, kBlk, 0, stream>>>(src, tgt, (const Rec4*)packf,
                                             keys, counter, out);
}

// Round 4
// 77.220 us; speedup vs baseline: 2.4120x; 2.4120x over previous
//
#include <hip/hip_runtime.h>

namespace {
constexpr int kB = 4;
constexpr int kN = 4096;             // points per set per batch (N == M)
constexpr int kPts = kB * kN;        // per set = 16384
constexpr int kP = 2 * kPts;         // all per-point mins = 32768
constexpr int kBlk = 256;
constexpr int kSplit = 16;           // blocks splitting the inner scan
constexpr int kChunk = kN / kSplit;  // 256 other-points per block
constexpr float kInf = 3.4e38f;
}

// ws layout: [keys: kP u32][pack: kP float4, 16B-aligned]
// pack[0 .. kPts)  = target points (x, y, z, ||p||^2)
// pack[kPts .. kP) = source points

// Monotone float<->uint map: unsigned atomicMin orders all floats (partial
// e = ||y||^2 - 2 x.y can be negative).
__device__ __forceinline__ unsigned enc(float f) {
  unsigned u = __float_as_uint(f);
  return (u & 0x80000000u) ? ~u : (u | 0x80000000u);
}
__device__ __forceinline__ float dec(unsigned k) {
  return __uint_as_float((k & 0x80000000u) ? (k ^ 0x80000000u) : ~k);
}

// Pack every point as (x, y, z, ||p||^2); init keys to +max; zero the output.
__global__ __launch_bounds__(kBlk) void cham_prep_kernel(
    const float* __restrict__ src, const float* __restrict__ tgt,
    float4* __restrict__ pack, unsigned* __restrict__ keys,
    float* __restrict__ out) {
  int i = blockIdx.x * kBlk + threadIdx.x;  // grid covers exactly kP
  const float* p =
      (i < kPts) ? (tgt + (size_t)i * 3) : (src + (size_t)(i - kPts) * 3);
  float x = p[0], y = p[1], z = p[2];
  pack[i] = make_float4(x, y, z, fmaf(x, x, fmaf(y, y, z * z)));
  keys[i] = 0xFFFFFFFFu;  // encodes +max for atomicMin
  if (i == 0) out[0] = 0.0f;
}

// One thread = one own point; scans a 256-point chunk of the other set.
// min||x-y||^2 = ||x||^2 + min(||y||^2 - 2 x.y). Inner pair: 1 wave-uniform
// s_load_dwordx4 (scalar pipe) + 3 v_fma + 1 v_min. Unroll 16 + 8 independent
// accumulators keeps ~16 scalar loads in flight to hide K$ latency.
// NO fences, NO fused reduce: R3 showed per-wave __threadfence (L2 writeback
// on multi-XCD) cost ~100 us. Kernel-boundary ordering handles visibility.
__global__ __launch_bounds__(kBlk) void cham_min_kernel(
    const float4* __restrict__ pack, unsigned* __restrict__ keys) {
  const int dir = blockIdx.z;  // 0: s->t (other = tgt = first half), 1: t->s
  const int b = blockIdx.y;
  const int chunk = blockIdx.x & (kSplit - 1);
  const int ntile = blockIdx.x >> 4;  // kSplit == 16
  const int n = ntile * kBlk + threadIdx.x;

  const float4* __restrict__ own = pack + (size_t)(dir ^ 1) * kPts;
  const float4* __restrict__ oth = pack + (size_t)dir * kPts;

  const float4 v = own[(size_t)b * kN + n];  // coalesced per-lane load
  const float nx = -2.0f * v.x, ny = -2.0f * v.y, nz = -2.0f * v.z;

  const float4* __restrict__ q = oth + (size_t)b * kN + chunk * kChunk;

  float e[8];
#pragma unroll
  for (int j = 0; j < 8; ++j) e[j] = kInf;

#pragma unroll 4
  for (int m = 0; m < kChunk; m += 16) {
    float4 t[16];
#pragma unroll
    for (int j = 0; j < 16; ++j) t[j] = q[m + j];  // batch the scalar loads
#pragma unroll
    for (int j = 0; j < 16; ++j) {
      float d = fmaf(nx, t[j].x, fmaf(ny, t[j].y, fmaf(nz, t[j].z, t[j].w)));
      e[j & 7] = fminf(e[j & 7], d);
    }
  }

  float b01 = fminf(fminf(e[0], e[1]), fminf(e[2], e[3]));
  float b23 = fminf(fminf(e[4], e[5]), fminf(e[6], e[7]));
  const float best = fminf(b01, b23) + v.w;

  atomicMin(&keys[((size_t)dir * kB + b) * kN + n], enc(best));
}

// Decode keys, sum all 2*B*N per-point mins, scale by 1/(B*N) (N == M).
__global__ __launch_bounds__(kBlk) void cham_reduce_kernel(
    const unsigned* __restrict__ keys, float* __restrict__ out) {
  __shared__ float red[kBlk];
  float acc = 0.0f;
  for (int i = blockIdx.x * kBlk + threadIdx.x; i < kP; i += gridDim.x * kBlk)
    acc += dec(keys[i]);
  red[threadIdx.x] = acc;
  __syncthreads();
  for (int s = kBlk / 2; s > 0; s >>= 1) {
    if (threadIdx.x < s) red[threadIdx.x] += red[threadIdx.x + s];
    __syncthreads();
  }
  if (threadIdx.x == 0) atomicAdd(out, red[0] * (1.0f / kPts));
}

extern "C" void kernel_launch(void* const* d_in, const int* in_sizes, int n_in,
                              void* d_out, int out_size, void* d_ws,
                              size_t ws_size, hipStream_t stream) {
  const float* src = (const float*)d_in[0];  // (B, N, 3) fp32
  const float* tgt = (const float*)d_in[1];  // (B, M, 3) fp32
  float* out = (float*)d_out;                // scalar fp32

  unsigned* keys = (unsigned*)d_ws;                         // 128 KB
  float4* pack = (float4*)((char*)d_ws + (size_t)kP * 4);   // 512 KB

  cham_prep_kernel<<<dim3(kP / kBlk), kBlk, 0, stream>>>(src, tgt, pack, keys,
                                                         out);

  // (16 tiles * 16 splits, B, 2 dirs) = 2048 blocks -> 8/CU, full occupancy
  dim3 grid(kN / kBlk * kSplit, kB, 2);
  cham_min_kernel<<<grid, kBlk, 0, stream>>>(pack, keys);

  cham_reduce_kernel<<<dim3(16), kBlk, 0, stream>>>(keys, out);
}

// Round 5
// 74.513 us; speedup vs baseline: 2.4996x; 1.0363x over previous
//
#include <hip/hip_runtime.h>

typedef float f2 __attribute__((ext_vector_type(2)));

namespace {
constexpr int kB = 4;
constexpr int kN = 4096;             // points per set per batch (N == M)
constexpr int kPts = kB * kN;        // per set = 16384
constexpr int kP = 2 * kPts;         // all per-point mins = 32768
constexpr int kBlk = 256;
constexpr int kSplit = 16;           // blocks splitting the inner scan
constexpr int kChunk = kN / kSplit;  // 256 other-points per block
constexpr float kInf = 3.4e38f;
}

// ws layout: [keys: kP u32][pack: kP float4 worth of pair-interleaved floats]
// Pair-interleaved pack: for point pair g, float4 pack4[2g] = {x0,x1,y0,y1},
// pack4[2g+1] = {z0,z1,w0,w1}, w = ||p||^2. Pairs [0, kPts/2) = target set,
// [kPts/2, kP/2) = source set. This layout puts v_pk_fma_f32 operands in
// adjacent registers after the wave-uniform s_load_dwordx4.

// Monotone float<->uint map: unsigned atomicMin orders all floats (partial
// e = ||y||^2 - 2 x.y can be negative).
__device__ __forceinline__ unsigned enc(float f) {
  unsigned u = __float_as_uint(f);
  return (u & 0x80000000u) ? ~u : (u | 0x80000000u);
}
__device__ __forceinline__ float dec(unsigned k) {
  return __uint_as_float((k & 0x80000000u) ? (k ^ 0x80000000u) : ~k);
}

// Pack points pair-interleaved; init keys to +max; zero the output.
__global__ __launch_bounds__(kBlk) void cham_prep_kernel(
    const float* __restrict__ src, const float* __restrict__ tgt,
    float* __restrict__ packf, unsigned* __restrict__ keys,
    float* __restrict__ out) {
  int i = blockIdx.x * kBlk + threadIdx.x;  // grid covers exactly kP
  const float* p =
      (i < kPts) ? (tgt + (size_t)i * 3) : (src + (size_t)(i - kPts) * 3);
  float x = p[0], y = p[1], z = p[2];
  float w = fmaf(x, x, fmaf(y, y, z * z));
  float* base = packf + (size_t)(i >> 1) * 8 + (i & 1);
  base[0] = x;
  base[2] = y;
  base[4] = z;
  base[6] = w;
  keys[i] = 0xFFFFFFFFu;  // encodes +max for atomicMin
  if (i == 0) out[0] = 0.0f;
}

// One thread = one own point; scans a 256-point chunk of the other set.
// min||x-y||^2 = ||x||^2 + min(||y||^2 - 2 x.y). Inner 2-point group:
// 2 wave-uniform s_load_dwordx4 + 3 v_pk_fma + 1 v_pk_add (W as separate add
// so each pk op reads <=1 SGPR operand) + 1 v_min3  => 2.5 VALU instr/pair.
// NO fences / fused reduce (R3: per-wave __threadfence cost ~100 us).
__global__ __launch_bounds__(kBlk) void cham_min_kernel(
    const float* __restrict__ src, const float* __restrict__ tgt,
    const float4* __restrict__ pack4, unsigned* __restrict__ keys) {
  const int dir = blockIdx.z;  // 0: s->t (other = tgt = first half), 1: t->s
  const int b = blockIdx.y;
  const int chunk = blockIdx.x & (kSplit - 1);
  const int ntile = blockIdx.x >> 4;  // kSplit == 16
  const int n = ntile * kBlk + threadIdx.x;

  const float* __restrict__ own = dir ? tgt : src;
  const float* p = own + ((size_t)b * kN + n) * 3;
  const float x = p[0], y = p[1], z = p[2];
  const float w = fmaf(x, x, fmaf(y, y, z * z));
  const f2 NX = {-2.0f * x, -2.0f * x};
  const f2 NY = {-2.0f * y, -2.0f * y};
  const f2 NZ = {-2.0f * z, -2.0f * z};

  // other-set chunk start, in 2-point groups (2 float4s per group)
  const size_t g0 = ((size_t)dir * kPts + (size_t)b * kN + chunk * kChunk) / 2;
  const float4* __restrict__ q = pack4 + 2 * g0;

  float e0 = kInf, e1 = kInf, e2 = kInf, e3 = kInf;
#pragma unroll 8
  for (int g = 0; g < kChunk / 2; ++g) {
    const float4 A = q[2 * g + 0];  // {x0, x1, y0, y1}
    const float4 Bv = q[2 * g + 1]; // {z0, z1, w0, w1}
    const f2 X = {A.x, A.y}, Y = {A.z, A.w};
    const f2 Z = {Bv.x, Bv.y}, W = {Bv.z, Bv.w};
    f2 e = __builtin_elementwise_fma(
               NX, X, __builtin_elementwise_fma(NY, Y, NZ * Z)) +
           W;
    float m = fminf(e.x, e.y);  // feeds v_min3 with the accumulator
    switch (g & 3) {
      case 0: e0 = fminf(e0, m); break;
      case 1: e1 = fminf(e1, m); break;
      case 2: e2 = fminf(e2, m); break;
      default: e3 = fminf(e3, m); break;
    }
  }

  const float best = fminf(fminf(e0, e1), fminf(e2, e3)) + w;
  atomicMin(&keys[((size_t)dir * kB + b) * kN + n], enc(best));
}

// Decode keys, sum all 2*B*N per-point mins, scale by 1/(B*N) (N == M).
__global__ __launch_bounds__(kBlk) void cham_reduce_kernel(
    const unsigned* __restrict__ keys, float* __restrict__ out) {
  __shared__ float red[kBlk];
  float acc = 0.0f;
  for (int i = blockIdx.x * kBlk + threadIdx.x; i < kP; i += gridDim.x * kBlk)
    acc += dec(keys[i]);
  red[threadIdx.x] = acc;
  __syncthreads();
  for (int s = kBlk / 2; s > 0; s >>= 1) {
    if (threadIdx.x < s) red[threadIdx.x] += red[threadIdx.x + s];
    __syncthreads();
  }
  if (threadIdx.x == 0) atomicAdd(out, red[0] * (1.0f / kPts));
}

extern "C" void kernel_launch(void* const* d_in, const int* in_sizes, int n_in,
                              void* d_out, int out_size, void* d_ws,
                              size_t ws_size, hipStream_t stream) {
  const float* src = (const float*)d_in[0];  // (B, N, 3) fp32
  const float* tgt = (const float*)d_in[1];  // (B, M, 3) fp32
  float* out = (float*)d_out;                // scalar fp32

  unsigned* keys = (unsigned*)d_ws;                        // 128 KB
  float* packf = (float*)((char*)d_ws + (size_t)kP * 4);   // 512 KB, 16B-align

  cham_prep_kernel<<<dim3(kP / kBlk), kBlk, 0, stream>>>(src, tgt, packf, keys,
                                                         out);

  // (16 tiles * 16 splits, B, 2 dirs) = 2048 blocks -> 8/CU, full occupancy
  dim3 grid(kN / kBlk * kSplit, kB, 2);
  cham_min_kernel<<<grid, kBlk, 0, stream>>>(src, tgt, (const float4*)packf,
                                             keys);

  cham_reduce_kernel<<<dim3(16), kBlk, 0, stream>>>(keys, out);
}